// Round 15
// baseline (86.130 us; speedup 1.0000x reference)
//
#include <hip/hip_runtime.h>
#include <hip/hip_bf16.h>
#include <stdint.h>

#define NROWS 32768
#define MCOLS 8192
#define DDIM  256

#define BM 128            // rows per workgroup
#define BN 64             // cols per tile (4 strips x 16)
#define NT 64             // tiles per block (4096-col half / 64)
#define NWG 512           // 256 row-blocks x 2 column halves = 2 blocks/CU

typedef __attribute__((ext_vector_type(8))) int   int8v;
typedef __attribute__((ext_vector_type(4))) float f32x4;

// pack 4 f32 -> 4 fp8 e4m3 (OCP) via HW converter (RNE, saturating)
__device__ __forceinline__ uint32_t pk4_fp8(float4 v) {
  int p = __builtin_amdgcn_cvt_pk_fp8_f32(v.x, v.y, 0, false);
  p = __builtin_amdgcn_cvt_pk_fp8_f32(v.z, v.w, p, true);
  return (uint32_t)p;
}
// order-preserving float -> uint key (integer atomicMin == float min)
__device__ __forceinline__ uint32_t fkey(float f) {
  uint32_t b = __float_as_uint(f);
  return (b & 0x80000000u) ? ~b : (b | 0x80000000u);
}
__device__ __forceinline__ float funkey(uint32_t k) {
  uint32_t b = (k & 0x80000000u) ? (k ^ 0x80000000u) : ~k;
  return __uint_as_float(b);
}
__device__ __forceinline__ f32x4 vmin4(f32x4 x, f32x4 y) {
  f32x4 r;
  r[0] = fminf(x[0], y[0]); r[1] = fminf(x[1], y[1]);
  r[2] = fminf(x[2], y[2]); r[3] = fminf(x[3], y[3]);
  return r;
}

// ---- K1: prep. XqN = row-major fp8 NEGATED (acc C-init = cj -> cj - x.y);
//          YqT = fragment-major fp8 transpose (r9/r14-verified mapping):
//          byte(col,k) = (col>>4)*4096 + (k>>7)*2048 + ((k>>5)&3)*512
//                        + (col&15)*32 + (k&31)
//          xhalf = 0.5||x||^2; cbuf = 0.5||y||^2 - psi; rowkey init.
__global__ void k_prep(const float* __restrict__ X, const float* __restrict__ Y,
                       const float* __restrict__ psi,
                       uint32_t* __restrict__ XqN, uint32_t* __restrict__ YqT,
                       float* __restrict__ xhalf, float* __restrict__ cbuf,
                       uint32_t* __restrict__ rowkey, float* __restrict__ sum_accum)
{
  const int lane = threadIdx.x & 63;
  const int gw = (blockIdx.x * blockDim.x + threadIdx.x) >> 6;
  const int nw = (gridDim.x * blockDim.x) >> 6;
  for (int row = gw; row < NROWS + MCOLS; row += nw) {
    const bool isX = row < NROWS;
    const int r = isX ? row : row - NROWS;
    const float* src = isX ? (X + (size_t)row * DDIM) : (Y + (size_t)r * DDIM);
    float4 v = ((const float4*)src)[lane];          // elements k = lane*4 .. +4
    const uint32_t pk = pk4_fp8(v);
    if (isX) {
      XqN[(size_t)row * 64 + lane] = pk ^ 0x80808080u;   // negate fp8
    } else {
      const int idx = (r >> 4) * 1024 + (lane >> 5) * 512 + ((lane >> 3) & 3) * 128
                    + (r & 15) * 8 + (lane & 7);         // uint32 units
      YqT[idx] = pk;
    }
    float s = v.x*v.x + v.y*v.y + v.z*v.z + v.w*v.w;
    #pragma unroll
    for (int m = 32; m >= 1; m >>= 1) s += __shfl_xor(s, m);
    if (lane == 0) {
      if (isX) { xhalf[row] = 0.5f * s; rowkey[row] = 0xFFFFFFFFu; }
      else     { cbuf[r] = 0.5f * s - psi[r]; }
    }
  }
  if (blockIdx.x == 0 && threadIdx.x == 0) sum_accum[0] = 0.0f;
}

// load tile t_'s B fragments for this wave's strip (32B/lane per kc) + cj
#define LOADB(dst, cjv, t_) do {                                                \
    const char* _p = bBase + (size_t)(t_) * 16384;                              \
    dst[0] = *(const int8v*)(_p);                                               \
    dst[1] = *(const int8v*)(_p + 2048);                                        \
    cjv = cjPtr[(t_) * BN];                                                     \
  } while (0)

// one tile: 8 MFMA on CUR with C-init = cj; then prefetch t_+2 into CUR; min.
#define STEP(t_, CUR, cjv) do {                                                 \
    const f32x4 _ci = {cjv, cjv, cjv, cjv};                                     \
    f32x4 acc[4];                                                               \
    __builtin_amdgcn_s_setprio(1);                                              \
    _Pragma("unroll") for (int _m = 0; _m < 4; ++_m)                            \
      acc[_m] = __builtin_amdgcn_mfma_scale_f32_16x16x128_f8f6f4(               \
          a[_m][0], CUR[0], _ci, 0, 0, 0, 0x7F, 0, 0x7F);                       \
    _Pragma("unroll") for (int _m = 0; _m < 4; ++_m)                            \
      acc[_m] = __builtin_amdgcn_mfma_scale_f32_16x16x128_f8f6f4(               \
          a[_m][1], CUR[1], acc[_m], 0, 0, 0, 0x7F, 0, 0x7F);                   \
    __builtin_amdgcn_s_setprio(0);                                              \
    if ((t_) + 2 < NT) LOADB(CUR, cjv, (t_) + 2);                               \
    _Pragma("unroll") for (int _m = 0; _m < 4; ++_m)                            \
      vmin[_m] = vmin4(vmin[_m], acc[_m]);                                      \
  } while (0)

// ---- K2: barrier-free, LDS-free main loop; 2 blocks/CU (column halves) give
//          4 waves/SIMD of out-of-phase overlap. 8 waves = 2 rg x 4 strips;
//          A (64 rows, negated) in regs; B streams global->reg via YqT.
__global__ __attribute__((amdgpu_flat_work_group_size(512, 512),
                          amdgpu_waves_per_eu(2, 4)))
void k_gemm(const uint32_t* __restrict__ XqN, const uint32_t* __restrict__ YqT,
            const float* __restrict__ cbuf, uint32_t* __restrict__ rowkey)
{
  __shared__ float Rw[4][BM];      // strip-min merge

  const int brow = (blockIdx.x >> 1) * BM;
  const int bcol = (blockIdx.x & 1) * (MCOLS / 2);
  const int tid  = threadIdx.x;
  const int wid  = tid >> 6;
  const int lane = tid & 63;
  const int rg    = wid >> 2;      // 0..1 -> rows rg*64
  const int strip = wid & 3;       // 0..3 -> cols strip*16 within each 64-tile
  const int c15 = lane & 15;
  const int w4  = lane >> 4;

  // A fragments (negated fp8): rows brow + rg*64 + m*16 + c15; bytes kc*128+w4*32
  int8v a[4][2];
  {
    const char* aBase = (const char*)XqN + ((size_t)(brow + rg * 64 + c15) << 8) + w4 * 32;
    #pragma unroll
    for (int m = 0; m < 4; ++m)
      #pragma unroll
      for (int kc = 0; kc < 2; ++kc)
        a[m][kc] = *(const int8v*)(aBase + m * 4096 + kc * 128);
  }

  // B fragment base for this column half + strip (32B/lane, coalesced)
  const char* bBase = (const char*)YqT + (size_t)(bcol >> 6) * 16384
                      + (size_t)strip * 4096 + (w4 * 16 + c15) * 32;
  const float* cjPtr = cbuf + bcol + strip * 16 + c15;

  int8v bA[2], bB[2];
  float cjA, cjB;
  LOADB(bA, cjA, 0);
  LOADB(bB, cjB, 1);

  f32x4 vmin[4];
  #pragma unroll
  for (int m = 0; m < 4; ++m)
    vmin[m] = (f32x4){3.4e38f, 3.4e38f, 3.4e38f, 3.4e38f};

  #pragma unroll 1
  for (int tt = 0; tt < NT; tt += 2) {
    STEP(tt,     bA, cjA);
    STEP(tt + 1, bB, cjB);
  }

  // epilogue: per-wave min over its 16 cols; merge strips via LDS; atomicMin
  // per row into rowkey. C/D layout: col = lane&15, row = (lane>>4)*4 + reg
  #pragma unroll
  for (int m = 0; m < 4; ++m) {
    #pragma unroll
    for (int r = 0; r < 4; ++r) {
      float v = vmin[m][r];
      v = fminf(v, __shfl_xor(v, 1));
      v = fminf(v, __shfl_xor(v, 2));
      v = fminf(v, __shfl_xor(v, 4));
      v = fminf(v, __shfl_xor(v, 8));
      vmin[m][r] = v;
    }
    if (c15 < 4) {
      float vsel = vmin[m][0];
      vsel = (c15 == 1) ? vmin[m][1] : vsel;
      vsel = (c15 == 2) ? vmin[m][2] : vsel;
      vsel = (c15 == 3) ? vmin[m][3] : vsel;
      Rw[strip][rg * 64 + m * 16 + w4 * 4 + c15] = vsel;
    }
  }
  __syncthreads();

  if (tid < BM) {
    float rm = fminf(fminf(Rw[0][tid], Rw[1][tid]),
                     fminf(Rw[2][tid], Rw[3][tid]));
    atomicMin((unsigned int*)&rowkey[brow + tid], fkey(rm));
  }
}

// ---- K3: sum over rows of (min + 0.5||x||^2)
__global__ void k_rowred(const float* __restrict__ xhalf, const uint32_t* __restrict__ rowkey,
                         float* __restrict__ sum_accum)
{
  __shared__ float sh[4];
  const int i = blockIdx.x * 256 + threadIdx.x;
  float v = funkey(rowkey[i]) + xhalf[i];
  #pragma unroll
  for (int m = 32; m >= 1; m >>= 1) v += __shfl_xor(v, m);
  const int wid = threadIdx.x >> 6, lane = threadIdx.x & 63;
  if (lane == 0) sh[wid] = v;
  __syncthreads();
  if (threadIdx.x == 0) atomicAdd(sum_accum, sh[0] + sh[1] + sh[2] + sh[3]);
}

// ---- K4: out = sum/N + mean(psi)
__global__ void k_final(const float* __restrict__ psi, const float* __restrict__ sum_accum,
                        float* __restrict__ out)
{
  __shared__ float sh[4];
  float s = 0.f;
  for (int i = threadIdx.x; i < MCOLS; i += 256) s += psi[i];
  #pragma unroll
  for (int m = 32; m >= 1; m >>= 1) s += __shfl_xor(s, m);
  const int wid = threadIdx.x >> 6, lane = threadIdx.x & 63;
  if (lane == 0) sh[wid] = s;
  __syncthreads();
  if (threadIdx.x == 0)
    out[0] = sum_accum[0] / (float)NROWS + (sh[0] + sh[1] + sh[2] + sh[3]) / (float)MCOLS;
}

extern "C" void kernel_launch(void* const* d_in, const int* in_sizes, int n_in,
                              void* d_out, int out_size, void* d_ws, size_t ws_size,
                              hipStream_t stream)
{
  const float* X   = (const float*)d_in[0];
  const float* Y   = (const float*)d_in[1];
  const float* psi = (const float*)d_in[2];
  float* out = (float*)d_out;

  char* ws = (char*)d_ws;
  uint32_t* XqN    = (uint32_t*)(ws);                                           // 8,388,608 B
  uint32_t* YqT    = (uint32_t*)(ws + (size_t)NROWS * DDIM);                    // 2,097,152 B
  float* cbuf      = (float*)(ws + (size_t)(NROWS + MCOLS) * DDIM);             //    32,768 B
  uint32_t* rowkey = (uint32_t*)((char*)cbuf + (size_t)MCOLS * 4);              //   131,072 B
  float* xhalf     = (float*)((char*)rowkey + (size_t)NROWS * 4);               //   131,072 B
  float* sum_accum = (float*)((char*)xhalf + (size_t)NROWS * 4);                //         4 B

  k_prep  <<<2048, 256, 0, stream>>>(X, Y, psi, XqN, YqT, xhalf, cbuf, rowkey, sum_accum);
  k_gemm  <<<NWG, 512, 0, stream>>>(XqN, YqT, cbuf, rowkey);
  k_rowred<<<NROWS / 256, 256, 0, stream>>>(xhalf, rowkey, sum_accum);
  k_final <<<1, 256, 0, stream>>>(psi, sum_accum, out);
}

// Round 16
// 79.814 us; speedup vs baseline: 1.0791x; 1.0791x over previous
//
#include <hip/hip_runtime.h>
#include <hip/hip_bf16.h>
#include <stdint.h>

#define NROWS 32768
#define MCOLS 8192
#define DDIM  256

#define BM 128            // rows per workgroup; block sweeps ALL cols
#define BN 64             // cols per tile (4 strips x 16)
#define NT (MCOLS/BN)     // 128 tiles
#define NWG (NROWS/BM)    // 256 workgroups = 1 per CU

typedef __attribute__((ext_vector_type(8))) int   int8v;
typedef __attribute__((ext_vector_type(4))) float f32x4;

// pack 4 f32 -> 4 fp8 e4m3 (OCP) via HW converter (RNE, saturating)
__device__ __forceinline__ uint32_t pk4_fp8(float4 v) {
  int p = __builtin_amdgcn_cvt_pk_fp8_f32(v.x, v.y, 0, false);
  p = __builtin_amdgcn_cvt_pk_fp8_f32(v.z, v.w, p, true);
  return (uint32_t)p;
}
__device__ __forceinline__ f32x4 vmin4(f32x4 x, f32x4 y) {
  f32x4 r;
  r[0] = fminf(x[0], y[0]); r[1] = fminf(x[1], y[1]);
  r[2] = fminf(x[2], y[2]); r[3] = fminf(x[3], y[3]);
  return r;
}

// ---- K1: prep. XqN = row-major fp8 NEGATED (acc C-init = cj -> cj - x.y);
//          YqT = fragment-major fp8 transpose (r9/r14-verified mapping):
//          byte(col,k) = (col>>4)*4096 + (k>>7)*2048 + ((k>>5)&3)*512
//                        + (col&15)*32 + (k&31)
//          xhalf = 0.5||x||^2; cbuf = 0.5||y||^2 - psi (exact fp32).
__global__ void k_prep(const float* __restrict__ X, const float* __restrict__ Y,
                       const float* __restrict__ psi,
                       uint32_t* __restrict__ XqN, uint32_t* __restrict__ YqT,
                       float* __restrict__ xhalf, float* __restrict__ cbuf,
                       float* __restrict__ sum_accum)
{
  const int lane = threadIdx.x & 63;
  const int gw = (blockIdx.x * blockDim.x + threadIdx.x) >> 6;
  const int nw = (gridDim.x * blockDim.x) >> 6;
  for (int row = gw; row < NROWS + MCOLS; row += nw) {
    const bool isX = row < NROWS;
    const int r = isX ? row : row - NROWS;
    const float* src = isX ? (X + (size_t)row * DDIM) : (Y + (size_t)r * DDIM);
    float4 v = ((const float4*)src)[lane];          // elements k = lane*4 .. +4
    const uint32_t pk = pk4_fp8(v);
    if (isX) {
      XqN[(size_t)row * 64 + lane] = pk ^ 0x80808080u;   // negate fp8
    } else {
      const int idx = (r >> 4) * 1024 + (lane >> 5) * 512 + ((lane >> 3) & 3) * 128
                    + (r & 15) * 8 + (lane & 7);         // uint32 units
      YqT[idx] = pk;
    }
    float s = v.x*v.x + v.y*v.y + v.z*v.z + v.w*v.w;
    #pragma unroll
    for (int m = 32; m >= 1; m >>= 1) s += __shfl_xor(s, m);
    if (lane == 0) {
      if (isX) xhalf[row] = 0.5f * s;
      else     cbuf[r] = 0.5f * s - psi[r];
    }
  }
  if (blockIdx.x == 0 && threadIdx.x == 0) sum_accum[0] = 0.0f;
}

// load tile t_'s B fragments for this wave's strip (32B/lane per kc) + cj
#define LOADB(dst, cjv, t_) do {                                                \
    const char* _p = bBase + (size_t)(t_) * 16384;                              \
    dst[0] = *(const int8v*)(_p);                                               \
    dst[1] = *(const int8v*)(_p + 2048);                                        \
    cjv = cjPtr[(t_) * BN];                                                     \
  } while (0)

// fused 2-tile body: ONE 16-MFMA cluster (8 independent acc chains) covering
// tiles t_ and t_+1, then both prefetches, then both vmin folds.
#define STEP2(t_) do {                                                          \
    const f32x4 _ciA = {cjA, cjA, cjA, cjA};                                    \
    const f32x4 _ciB = {cjB, cjB, cjB, cjB};                                    \
    f32x4 accA[4], accB[4];                                                     \
    __builtin_amdgcn_s_setprio(1);                                              \
    _Pragma("unroll") for (int _m = 0; _m < 4; ++_m)                            \
      accA[_m] = __builtin_amdgcn_mfma_scale_f32_16x16x128_f8f6f4(              \
          a[_m][0], bA[0], _ciA, 0, 0, 0, 0x7F, 0, 0x7F);                       \
    _Pragma("unroll") for (int _m = 0; _m < 4; ++_m)                            \
      accB[_m] = __builtin_amdgcn_mfma_scale_f32_16x16x128_f8f6f4(              \
          a[_m][0], bB[0], _ciB, 0, 0, 0, 0x7F, 0, 0x7F);                       \
    _Pragma("unroll") for (int _m = 0; _m < 4; ++_m)                            \
      accA[_m] = __builtin_amdgcn_mfma_scale_f32_16x16x128_f8f6f4(              \
          a[_m][1], bA[1], accA[_m], 0, 0, 0, 0x7F, 0, 0x7F);                   \
    _Pragma("unroll") for (int _m = 0; _m < 4; ++_m)                            \
      accB[_m] = __builtin_amdgcn_mfma_scale_f32_16x16x128_f8f6f4(              \
          a[_m][1], bB[1], accB[_m], 0, 0, 0, 0x7F, 0, 0x7F);                   \
    __builtin_amdgcn_s_setprio(0);                                              \
    if ((t_) + 2 < NT) LOADB(bA, cjA, (t_) + 2);                                \
    if ((t_) + 3 < NT) LOADB(bB, cjB, (t_) + 3);                                \
    _Pragma("unroll") for (int _m = 0; _m < 4; ++_m)                            \
      vmin[_m] = vmin4(vmin[_m], vmin4(accA[_m], accB[_m]));                    \
  } while (0)

// ---- K2: barrier-free, LDS-free main loop. 8 waves = 2 row-groups x 4
//          col-strips; A (64 rows, negated) in regs; B streams global->reg
//          from L2 via YqT (dbuf, 2-tile skew); fused 16-MFMA clusters.
__global__ __attribute__((amdgpu_flat_work_group_size(512, 512),
                          amdgpu_waves_per_eu(2, 2)))
void k_gemm(const uint32_t* __restrict__ XqN, const uint32_t* __restrict__ YqT,
            const float* __restrict__ cbuf, const float* __restrict__ xhalf,
            float* __restrict__ sum_accum)
{
  __shared__ float Rw[4][BM];      // strip-min merge
  __shared__ float part[2];

  const int brow = blockIdx.x * BM;
  const int tid  = threadIdx.x;
  const int wid  = tid >> 6;
  const int lane = tid & 63;
  const int rg    = wid >> 2;      // 0..1 -> rows rg*64
  const int strip = wid & 3;       // 0..3 -> cols strip*16 within each 64-tile
  const int c15 = lane & 15;
  const int w4  = lane >> 4;

  // A fragments (negated fp8): rows brow + rg*64 + m*16 + c15; bytes kc*128+w4*32
  int8v a[4][2];
  {
    const char* aBase = (const char*)XqN + ((size_t)(brow + rg * 64 + c15) << 8) + w4 * 32;
    #pragma unroll
    for (int m = 0; m < 4; ++m)
      #pragma unroll
      for (int kc = 0; kc < 2; ++kc)
        a[m][kc] = *(const int8v*)(aBase + m * 4096 + kc * 128);
  }

  // B fragment base: tile t, kc -> bBase + t*16384 + kc*2048 (32B/lane, coalesced)
  const char* bBase = (const char*)YqT + (size_t)strip * 4096 + (w4 * 16 + c15) * 32;
  const float* cjPtr = cbuf + strip * 16 + c15;

  int8v bA[2], bB[2];
  float cjA, cjB;
  LOADB(bA, cjA, 0);
  LOADB(bB, cjB, 1);

  f32x4 vmin[4];
  #pragma unroll
  for (int m = 0; m < 4; ++m)
    vmin[m] = (f32x4){3.4e38f, 3.4e38f, 3.4e38f, 3.4e38f};

  #pragma unroll 1
  for (int tt = 0; tt < NT; tt += 2) {
    STEP2(tt);
  }

  // epilogue: per-wave min over its 16 cols; merge strips via LDS; sum rows.
  // C/D layout: col = lane&15, row = (lane>>4)*4 + reg
  #pragma unroll
  for (int m = 0; m < 4; ++m) {
    #pragma unroll
    for (int r = 0; r < 4; ++r) {
      float v = vmin[m][r];
      v = fminf(v, __shfl_xor(v, 1));
      v = fminf(v, __shfl_xor(v, 2));
      v = fminf(v, __shfl_xor(v, 4));
      v = fminf(v, __shfl_xor(v, 8));
      vmin[m][r] = v;
    }
    if (c15 < 4) {
      float vsel = vmin[m][0];
      vsel = (c15 == 1) ? vmin[m][1] : vsel;
      vsel = (c15 == 2) ? vmin[m][2] : vsel;
      vsel = (c15 == 3) ? vmin[m][3] : vsel;
      Rw[strip][rg * 64 + m * 16 + w4 * 4 + c15] = vsel;
    }
  }
  __syncthreads();

  if (tid < BM) {
    float rm = fminf(fminf(Rw[0][tid], Rw[1][tid]),
                     fminf(Rw[2][tid], Rw[3][tid]));
    float s = rm + xhalf[brow + tid];
    #pragma unroll
    for (int m = 32; m >= 1; m >>= 1) s += __shfl_xor(s, m);
    if (lane == 0) part[wid] = s;
  }
  __syncthreads();
  if (tid == 0) atomicAdd(sum_accum, part[0] + part[1]);
}

// ---- K3: out = sum/N + mean(psi)
__global__ void k_final(const float* __restrict__ psi, const float* __restrict__ sum_accum,
                        float* __restrict__ out)
{
  __shared__ float sh[4];
  float s = 0.f;
  for (int i = threadIdx.x; i < MCOLS; i += 256) s += psi[i];
  #pragma unroll
  for (int m = 32; m >= 1; m >>= 1) s += __shfl_xor(s, m);
  const int wid = threadIdx.x >> 6, lane = threadIdx.x & 63;
  if (lane == 0) sh[wid] = s;
  __syncthreads();
  if (threadIdx.x == 0)
    out[0] = sum_accum[0] / (float)NROWS + (sh[0] + sh[1] + sh[2] + sh[3]) / (float)MCOLS;
}

extern "C" void kernel_launch(void* const* d_in, const int* in_sizes, int n_in,
                              void* d_out, int out_size, void* d_ws, size_t ws_size,
                              hipStream_t stream)
{
  const float* X   = (const float*)d_in[0];
  const float* Y   = (const float*)d_in[1];
  const float* psi = (const float*)d_in[2];
  float* out = (float*)d_out;

  char* ws = (char*)d_ws;
  uint32_t* XqN    = (uint32_t*)(ws);                                           // 8,388,608 B
  uint32_t* YqT    = (uint32_t*)(ws + (size_t)NROWS * DDIM);                    // 2,097,152 B
  float* cbuf      = (float*)(ws + (size_t)(NROWS + MCOLS) * DDIM);             //    32,768 B
  float* xhalf     = (float*)((char*)cbuf + (size_t)MCOLS * 4);                 //   131,072 B
  float* sum_accum = (float*)((char*)xhalf + (size_t)NROWS * 4);                //         4 B

  k_prep <<<2048, 256, 0, stream>>>(X, Y, psi, XqN, YqT, xhalf, cbuf, sum_accum);
  k_gemm <<<NWG, 512, 0, stream>>>(XqN, YqT, cbuf, xhalf, sum_accum);
  k_final<<<1, 256, 0, stream>>>(psi, sum_accum, out);
}